// Round 3
// baseline (6908.265 us; speedup 1.0000x reference)
//
#include <hip/hip_runtime.h>

// Problem constants: T=2048, B=256, F=64, H=256, O=1
#define T_STEPS 2048
#define BATCH   256
#define FEAT    64
#define HID     256
#define KAUG    320   // FEAT + HID
#define NW      8     // waves per block
#define NTHR    512   // 8 waves = 2 waves/SIMD, grid 256 = 1 block/CU
#define XTILE   16    // timesteps per x staging tile

typedef _Float16 half8 __attribute__((ext_vector_type(8)));
typedef float    f32x4 __attribute__((ext_vector_type(4)));
typedef float    f32x8 __attribute__((ext_vector_type(8)));

// fast tanh: tanh(z) = 1 - 2/(exp(2z)+1). Saturates correctly at +/-inf.
__device__ __forceinline__ float fast_tanh(float z) {
    float e = __expf(2.0f * z);
    return 1.0f - 2.0f * __builtin_amdgcn_rcpf(e + 1.0f);
}

// R3: kill the LDS A-broadcast (R2's bottleneck: 8 waves x 10 ds_read_b128 =
// 80 KB/step of register-fill through a ~128 B/clk LDS return path = ~640
// cyc/step, all 8x-redundant).
//  - Only A-row 0 feeds C-row 0; A-row 0 lives in lanes {0,16,32,48} only
//    (A-frag: lane l holds A[l&15][(l>>4)*8+e]). So A-loads are exec-masked
//    to 4 lanes/wave; other lanes' A-regs are don't-cares feeding discarded
//    C rows 1..15 (MFMA gathers operands as matrices; EXEC masks D only).
//  - K-split across waves: wave w owns h-chunk w (a-idx 64+32w..+31) for all
//    16 N-tiles + x-chunk (w>>2) for 4 tiles -> balanced 20 independent
//    MFMAs/wave. Partials cross-wave-reduced via ds_add_f32 atomics into
//    double-buffered f32 h_acc[2][256] (double buffer = zero-restore by the
//    reader cannot race next step's adds; barrier-separated).
//  - Next step's A-lanes read raw z, do bias+tanh+f16-pack IN-LANE: no h_buf,
//    no broadcast, no second barrier. fc1 rides the same tanh values and is
//    deferred one step (out_buf[t-1]) -> off the critical path.
//  - C starts from a loop-invariant zero reg: no per-step acc re-init VALU.
__global__
__attribute__((amdgpu_flat_work_group_size(NTHR, NTHR), amdgpu_waves_per_eu(2, 2)))
void rnn_kernel(const float* __restrict__ x,    // (T, B, F)
                const float* __restrict__ W0,   // (H, F+H) row-major
                const float* __restrict__ b0,   // (H)
                const float* __restrict__ Wfc,  // (1, H)
                const float* __restrict__ bfc,  // (1)
                float* __restrict__ out)        // (B, T)
{
    const int b    = blockIdx.x;
    const int tid  = threadIdx.x;
    const int w    = tid >> 6;
    const int lane = tid & 63;
    const int l15  = lane & 15;
    const int kg   = lane >> 4;         // k-group 0..3
    const int ntb  = 4 * (w & 3);       // local tile base; global tile = ntb ^ i
    const int xc   = w >> 2;            // x-chunk (0 or 1) owned by this wave
    const bool alane = (l15 == 0);      // lanes 0,16,32,48: hold A-row 0

    __shared__ __align__(16) float    h_acc[2][HID];            // z accumulators, 2 KB
    __shared__ __align__(16) _Float16 x_tile[2][XTILE][FEAT];   // 4 KB
    __shared__ __align__(16) float    out_buf[T_STEPS];         // 8 KB

    // ---- B-frags: bh[i] = W0 rows of tile (ntb^i), this wave's h-chunk;
    // bx[j] = tiles (ntb^j), j<4 (ntb^j == ntb+j for j<4), x-chunk xc.
    // 20 frags = 80 regs/lane.
    half8 bh[16], bx[4];
    const int khb = FEAT + 32 * w + kg * 8;   // h-chunk a-index for this lane
    const int kxb = xc * 32 + kg * 8;         // x-chunk a-index
#pragma unroll
    for (int i = 0; i < 16; ++i) {
        const int n = (ntb ^ i) * 16 + l15;
        const f32x8 v = *reinterpret_cast<const f32x8*>(W0 + n * KAUG + khb);
        bh[i] = __builtin_convertvector(v, half8);
    }
#pragma unroll
    for (int j = 0; j < 4; ++j) {
        const int n = (ntb ^ j) * 16 + l15;
        const f32x8 v = *reinterpret_cast<const f32x8*>(W0 + n * KAUG + kxb);
        bx[j] = __builtin_convertvector(v, half8);
    }

    // A-lane constants: bias + fc weight for its 8 neurons (hb = 32w + 8kg)
    const int hb = 32 * w + kg * 8;
    f32x4 b0a = {}, b0b = {}, wfa = {}, wfb = {};
    if (alane) {
        b0a = *reinterpret_cast<const f32x4*>(b0 + hb);
        b0b = *reinterpret_cast<const f32x4*>(b0 + hb + 4);
        wfa = *reinterpret_cast<const f32x4*>(Wfc + hb);
        wfb = *reinterpret_cast<const f32x4*>(Wfc + hb + 4);
    }
    const float bfc_r = bfc[0];

    // ---- prologue: h_acc = 0 (both buffers), out_buf = bfc, stage x tile 0
    if (tid < HID) { h_acc[0][tid] = 0.f; h_acc[1][tid] = 0.f; }
#pragma unroll
    for (int i = 0; i < T_STEPS / NTHR; ++i) out_buf[tid + i * NTHR] = bfc_r;

    const int tr = tid >> 5;          // 0..15: timestep-row within x tile
    const int f2 = (tid & 31) * 2;    // 0..62: feature pair
    {
        const float2 v = *reinterpret_cast<const float2*>(
            x + (size_t)tr * (BATCH * FEAT) + b * FEAT + f2);
        union { _Float16 h[2]; unsigned u; } pk;
        pk.h[0] = (_Float16)v.x; pk.h[1] = (_Float16)v.y;
        *reinterpret_cast<unsigned*>(&x_tile[0][tr][f2]) = pk.u;
    }
    __syncthreads();

    const f32x4 zero4 = {0.f, 0.f, 0.f, 0.f};

    for (int t = 0; t < T_STEPS; ++t) {
        const int cur  = t & 1;
        const int prev = cur ^ 1;
        const int xb   = (t >> 4) & 1;

        // stage x tile for steps t+16..t+31 (load early, LDS-write late)
        const bool do_stage = ((t & 15) == 0) && (t + XTILE < T_STEPS);
        float2 xld;
        if (do_stage) {
            xld = *reinterpret_cast<const float2*>(
                x + (size_t)(t + XTILE + tr) * (BATCH * FEAT) + b * FEAT + f2);
        }

        // ---- A-frags. afx: wave-uniform-per-group broadcast read (cheap).
        const half8 afx = *reinterpret_cast<const half8*>(&x_tile[xb][t & 15][kxb]);

        // afh: A-lanes only — read raw z(t-1), zero-restore the buffer for
        // reuse at t+1, bias+tanh+pack; also the deferred fc1 partial.
        half8 afh = {};          // zero for t==0 and non-A-lanes (rows 1-15 don't care)
        float p = 0.f;
        if (alane && t > 0) {
            const f32x4 z0 = *reinterpret_cast<const f32x4*>(&h_acc[prev][hb]);
            const f32x4 z1 = *reinterpret_cast<const f32x4*>(&h_acc[prev][hb + 4]);
            *reinterpret_cast<f32x4*>(&h_acc[prev][hb])     = zero4;
            *reinterpret_cast<f32x4*>(&h_acc[prev][hb + 4]) = zero4;
            const float h0 = fast_tanh(z0.x + b0a.x);
            const float h1 = fast_tanh(z0.y + b0a.y);
            const float h2 = fast_tanh(z0.z + b0a.z);
            const float h3 = fast_tanh(z0.w + b0a.w);
            const float h4 = fast_tanh(z1.x + b0b.x);
            const float h5 = fast_tanh(z1.y + b0b.y);
            const float h6 = fast_tanh(z1.z + b0b.z);
            const float h7 = fast_tanh(z1.w + b0b.w);
            p = h0 * wfa.x + h1 * wfa.y + h2 * wfa.z + h3 * wfa.w
              + h4 * wfb.x + h5 * wfb.y + h6 * wfb.z + h7 * wfb.w;
            afh[0] = (_Float16)h0; afh[1] = (_Float16)h1;
            afh[2] = (_Float16)h2; afh[3] = (_Float16)h3;
            afh[4] = (_Float16)h4; afh[5] = (_Float16)h5;
            afh[6] = (_Float16)h6; afh[7] = (_Float16)h7;
        }

        // ---- MFMA: x-part first (no z dependency — fills the tanh shadow),
        // then h-part; all 16 accs independent, chains of <=2.
        f32x4 acc[16];
#pragma unroll
        for (int j = 0; j < 4; ++j)
            acc[j] = __builtin_amdgcn_mfma_f32_16x16x32_f16(afx, bx[j], zero4, 0, 0, 0);
#pragma unroll
        for (int j = 0; j < 4; ++j)
            acc[j] = __builtin_amdgcn_mfma_f32_16x16x32_f16(afh, bh[j], acc[j], 0, 0, 0);
#pragma unroll
        for (int i = 4; i < 16; ++i)
            acc[i] = __builtin_amdgcn_mfma_f32_16x16x32_f16(afh, bh[i], zero4, 0, 0, 0);

        // stage-write the prefetched x pair into the other tile buffer
        if (do_stage) {
            union { _Float16 h[2]; unsigned u; } pk;
            pk.h[0] = (_Float16)xld.x; pk.h[1] = (_Float16)xld.y;
            *reinterpret_cast<unsigned*>(&x_tile[xb ^ 1][tr][f2]) = pk.u;
        }

        // ---- deferred fc1 for out[t-1]: combine the 4 A-lanes (xor 16, 32)
        p += __shfl_xor(p, 16, 64);
        p += __shfl_xor(p, 32, 64);
        if (lane == 0 && t > 0) atomicAdd(&out_buf[t - 1], p);

        // ---- cross-wave partial reduction: C row 0 = lanes 0..15, reg 0
        if (lane < 16) {
#pragma unroll
            for (int i = 0; i < 16; ++i)
                atomicAdd(&h_acc[cur][(ntb ^ i) * 16 + lane], acc[i][0]);
        }

        __syncthreads();   // z(t) settled; zeroed prev-buffer ready for t+1
    }

    // ---- final output: out[T-1] from z(T-1) (in h_acc[(T-1)&1] = h_acc[1])
    {
        float p = 0.f;
        if (alane) {
            const f32x4 z0 = *reinterpret_cast<const f32x4*>(&h_acc[1][hb]);
            const f32x4 z1 = *reinterpret_cast<const f32x4*>(&h_acc[1][hb + 4]);
            const float h0 = fast_tanh(z0.x + b0a.x);
            const float h1 = fast_tanh(z0.y + b0a.y);
            const float h2 = fast_tanh(z0.z + b0a.z);
            const float h3 = fast_tanh(z0.w + b0a.w);
            const float h4 = fast_tanh(z1.x + b0b.x);
            const float h5 = fast_tanh(z1.y + b0b.y);
            const float h6 = fast_tanh(z1.z + b0b.z);
            const float h7 = fast_tanh(z1.w + b0b.w);
            p = h0 * wfa.x + h1 * wfa.y + h2 * wfa.z + h3 * wfa.w
              + h4 * wfb.x + h5 * wfb.y + h6 * wfb.z + h7 * wfb.w;
        }
        p += __shfl_xor(p, 16, 64);
        p += __shfl_xor(p, 32, 64);
        if (lane == 0) atomicAdd(&out_buf[T_STEPS - 1], p);
    }
    __syncthreads();

    // ---- epilogue: coalesced float4 store of the block's 2048 outputs
    f32x4* o4 = reinterpret_cast<f32x4*>(out + b * T_STEPS);
    const f32x4* s4 = reinterpret_cast<const f32x4*>(out_buf);
    o4[tid] = s4[tid];
}

extern "C" void kernel_launch(void* const* d_in, const int* in_sizes, int n_in,
                              void* d_out, int out_size, void* d_ws, size_t ws_size,
                              hipStream_t stream) {
    const float* x   = (const float*)d_in[0];
    const float* W0  = (const float*)d_in[1];
    const float* b0  = (const float*)d_in[2];
    const float* Wfc = (const float*)d_in[3];
    const float* bfc = (const float*)d_in[4];
    // d_in[5] = feature_n == 0 -> no autoregressive tail
    float* out = (float*)d_out;

    rnn_kernel<<<dim3(BATCH), dim3(NTHR), 0, stream>>>(x, W0, b0, Wfc, bfc, out);
}

// Round 4
// 1727.411 us; speedup vs baseline: 3.9992x; 3.9992x over previous
//
#include <hip/hip_runtime.h>

// Problem constants: T=2048, B=256, F=64, H=256, O=1
#define T_STEPS 2048
#define BATCH   256
#define FEAT    64
#define HID     256
#define KAUG    320   // FEAT + HID
#define NW      4     // 4 fat waves, 1 wave/SIMD, grid 256 = 1 block/CU
#define NTHR    256
#define XTILE   16    // timesteps per x staging tile

typedef _Float16 half8 __attribute__((ext_vector_type(8)));
typedef _Float16 half4 __attribute__((ext_vector_type(4)));
typedef float    f32x4 __attribute__((ext_vector_type(4)));
typedef float    f32x8 __attribute__((ext_vector_type(8)));

// fast tanh: tanh(z) = 1 - 2/(exp(2z)+1). Saturates correctly at +/-inf.
__device__ __forceinline__ float fast_tanh(float z) {
    float e = __expf(2.0f * z);
    return 1.0f - 2.0f * __builtin_amdgcn_rcpf(e + 1.0f);
}

// R4: R2's topology (wave owns whole neurons, full K -> NO cross-wave
// reduction) + R3's proven exec-masked A-loads, minus R3's LDS atomics
// (the 4x regression: 4096 lane-atomics/step, 8 waves contending per addr).
//  - 4 fat waves; wave w owns neurons [64w,64w+64) = 4 N-tiles x 10 K-chunks
//    = 160 VGPRs of B-frags. waves_per_eu(1,1) => 512-reg budget; MFMA reads
//    AGPRs natively so wherever the allocator parks them is free (R1 lesson).
//  - A-frag reads exec-masked to lanes {0,16,32,48} (only A-row 0 feeds the
//    C-row 0 we keep; R3 PASSED => masked-lane garbage rows are safe).
//    Non-alane af[] lanes hold persistent zeros (init before loop).
//    LDS read traffic/step: 80 KB (R2) -> 2.5 KB.
//  - fc1: no atomic. p reduced over lanes 0..15 via 4 shfl_xor, but DEFERRED
//    one step so the chain (~120 cyc serial) hides under the next step's
//    h-read latency + MFMA issue. Per-wave slot out_part[w][t]; summed once
//    in the final epilogue.
//  - x-chunk MFMAs (chunks 0,1) depend only on x_tile -> issue right after
//    the barrier, filling the h ds_read latency window.
//  - One barrier per step.
__global__
__attribute__((amdgpu_flat_work_group_size(NTHR, NTHR), amdgpu_waves_per_eu(1, 1)))
void rnn_kernel(const float* __restrict__ x,    // (T, B, F)
                const float* __restrict__ W0,   // (H, F+H) row-major
                const float* __restrict__ b0,   // (H)
                const float* __restrict__ Wfc,  // (1, H)
                const float* __restrict__ bfc,  // (1)
                float* __restrict__ out)        // (B, T)
{
    const int b    = blockIdx.x;
    const int tid  = threadIdx.x;
    const int w    = tid >> 6;
    const int lane = tid & 63;
    const int l15  = lane & 15;
    const int kg   = lane >> 4;          // k-group 0..3
    const bool alane = (l15 == 0);       // lanes 0,16,32,48: carry A-row 0

    __shared__ __align__(16) _Float16 h_buf[2][HID];            // 1 KB
    __shared__ __align__(16) _Float16 x_tile[2][XTILE][FEAT];   // 4 KB
    __shared__ __align__(16) float    out_part[NW][T_STEPS];    // 32 KB

    // ---- B-frags: wave w, tile j -> neurons (4w+j)*16 + l15; lane holds
    // W0[n][c*32 + kg*8 + e] as 8 f16. 40 frags = 160 regs/lane.
    half8 bw[4][10];
#pragma unroll
    for (int j = 0; j < 4; ++j) {
        const int n = (4 * w + j) * 16 + l15;
        const float* wp = W0 + n * KAUG + kg * 8;
#pragma unroll
        for (int c = 0; c < 10; ++c) {
            const f32x8 v = *reinterpret_cast<const f32x8*>(wp + c * 32);
            bw[j][c] = __builtin_convertvector(v, half8);
        }
    }

    // epilogue constants (C-row-0 lives on lanes 0..15): neuron (4w+j)*16+lane
    float b0e[4] = {}, wfe[4] = {};
    if (lane < 16) {
#pragma unroll
        for (int j = 0; j < 4; ++j) {
            b0e[j] = b0[(4 * w + j) * 16 + lane];
            wfe[j] = Wfc[(4 * w + j) * 16 + lane];
        }
    }

    // ---- prologue: h_buf = 0, stage x tile 0 (steps 0..15)
    if (tid < HID) { h_buf[0][tid] = (_Float16)0.f; h_buf[1][tid] = (_Float16)0.f; }
    {
        const int tr = tid >> 4, f4 = (tid & 15) * 4;
        const f32x4 v = *reinterpret_cast<const f32x4*>(
            x + (size_t)tr * (BATCH * FEAT) + b * FEAT + f4);
        const half4 hv = {(_Float16)v.x, (_Float16)v.y, (_Float16)v.z, (_Float16)v.w};
        *reinterpret_cast<half4*>(&x_tile[0][tr][f4]) = hv;
    }
    __syncthreads();

    // A-frags persist across iterations: non-alane lanes keep these zeros
    // forever (their values feed only discarded C rows 1..15).
    half8 af[10];
#pragma unroll
    for (int c = 0; c < 10; ++c) af[c] = half8{};

    float p_prev = 0.f;   // deferred fc1 partial from step t-1 (lanes 0..15)
    const f32x4 zero4 = {0.f, 0.f, 0.f, 0.f};

    for (int t = 0; t < T_STEPS; ++t) {
        const int cur = t & 1;
        const int nxt = cur ^ 1;
        const int xb  = (t >> 4) & 1;

        // x staging every 16 steps: global load issued early, LDS write late
        const bool do_stage = ((t & 15) == 0) && (t + XTILE < T_STEPS);
        const int tr = tid >> 4, f4 = (tid & 15) * 4;
        f32x4 xld = zero4;
        if (do_stage) {
            xld = *reinterpret_cast<const f32x4*>(
                x + (size_t)(t + XTILE + tr) * (BATCH * FEAT) + b * FEAT + f4);
        }

        // ---- A-frag reads, exec-masked to 4 lanes/wave (~64B each)
        if (alane) {
            af[0] = *reinterpret_cast<const half8*>(&x_tile[xb][t & 15][kg * 8]);
            af[1] = *reinterpret_cast<const half8*>(&x_tile[xb][t & 15][32 + kg * 8]);
#pragma unroll
            for (int c = 2; c < 10; ++c)
                af[c] = *reinterpret_cast<const half8*>(&h_buf[cur][(c - 2) * 32 + kg * 8]);
        }

        // ---- deferred fc1 reduce for step t-1: 4-deep shuffle chain runs in
        // the shadow of the h-read latency + MFMA issue (independent of both).
        {
            float p = p_prev;
            p += __shfl_xor(p, 1, 64);
            p += __shfl_xor(p, 2, 64);
            p += __shfl_xor(p, 4, 64);
            p += __shfl_xor(p, 8, 64);
            if (lane == 0) out_part[w][(t + T_STEPS - 1) & (T_STEPS - 1)] = p;
        }

        // ---- MFMA: 8 independent chains (4 tiles x even/odd chunks), depth 5.
        // x-chunks (0,1) first: no dependence on this step's h -> fill latency.
        f32x4 aE[4], aO[4];
#pragma unroll
        for (int j = 0; j < 4; ++j) {
            aE[j] = __builtin_amdgcn_mfma_f32_16x16x32_f16(af[0], bw[j][0], zero4, 0, 0, 0);
            aO[j] = __builtin_amdgcn_mfma_f32_16x16x32_f16(af[1], bw[j][1], zero4, 0, 0, 0);
        }
#pragma unroll
        for (int c = 2; c < 10; c += 2) {
#pragma unroll
            for (int j = 0; j < 4; ++j) {
                aE[j] = __builtin_amdgcn_mfma_f32_16x16x32_f16(af[c],     bw[j][c],     aE[j], 0, 0, 0);
                aO[j] = __builtin_amdgcn_mfma_f32_16x16x32_f16(af[c + 1], bw[j][c + 1], aO[j], 0, 0, 0);
            }
        }

        // stage-write prefetched x into the other tile buffer (read at t+16)
        if (do_stage) {
            const half4 hv = {(_Float16)xld.x, (_Float16)xld.y,
                              (_Float16)xld.z, (_Float16)xld.w};
            *reinterpret_cast<half4*>(&x_tile[xb ^ 1][tr][f4]) = hv;
        }

        // ---- epilogue: C-row 0 = lanes 0..15, reg 0 (m89-verified layout)
        float pnew = 0.f;
        if (lane < 16) {
#pragma unroll
            for (int j = 0; j < 4; ++j) {
                const float z = aE[j][0] + aO[j][0] + b0e[j];
                const float h = fast_tanh(z);
                pnew = fmaf(wfe[j], h, pnew);
                h_buf[nxt][(4 * w + j) * 16 + lane] = (_Float16)h;
            }
        }
        p_prev = pnew;

        __syncthreads();   // h(t) + x_tile settled; one barrier/step
    }

    // tail: reduce the final step's fc1 partial
    {
        float p = p_prev;
        p += __shfl_xor(p, 1, 64);
        p += __shfl_xor(p, 2, 64);
        p += __shfl_xor(p, 4, 64);
        p += __shfl_xor(p, 8, 64);
        if (lane == 0) out_part[w][T_STEPS - 1] = p;
    }
    __syncthreads();

    // ---- final epilogue: out[b][t] = bfc + sum_w out_part[w][t]
    const float bfc_r = bfc[0];
#pragma unroll
    for (int i = 0; i < 2; ++i) {
        const int t0 = tid * 8 + i * 4;
        f32x4 s = {bfc_r, bfc_r, bfc_r, bfc_r};
#pragma unroll
        for (int ww = 0; ww < NW; ++ww)
            s += *reinterpret_cast<const f32x4*>(&out_part[ww][t0]);
        *reinterpret_cast<f32x4*>(out + b * T_STEPS + t0) = s;
    }
}

extern "C" void kernel_launch(void* const* d_in, const int* in_sizes, int n_in,
                              void* d_out, int out_size, void* d_ws, size_t ws_size,
                              hipStream_t stream) {
    const float* x   = (const float*)d_in[0];
    const float* W0  = (const float*)d_in[1];
    const float* b0  = (const float*)d_in[2];
    const float* Wfc = (const float*)d_in[3];
    const float* bfc = (const float*)d_in[4];
    // d_in[5] = feature_n == 0 -> no autoregressive tail
    float* out = (float*)d_out;

    rnn_kernel<<<dim3(BATCH), dim3(NTHR), 0, stream>>>(x, W0, b0, Wfc, bfc, out);
}